// Round 1
// baseline (323.582 us; speedup 1.0000x reference)
//
#include <hip/hip_runtime.h>

typedef float f32x4 __attribute__((ext_vector_type(4)));
typedef short bf16x8 __attribute__((ext_vector_type(8)));
typedef unsigned short u16x4 __attribute__((ext_vector_type(4)));

#define BB 2
#define SS 2048
#define DM 1024
#define NH 16
#define DKH 64
#define MROWS 4096  // B*S

// RNE fp32 -> bf16
__device__ __forceinline__ unsigned short f2bf(float x) {
  union { float f; unsigned int u; } v; v.f = x;
  unsigned int r = v.u + 0x7fffu + ((v.u >> 16) & 1u);
  return (unsigned short)(r >> 16);
}

// async global->LDS, 16B per lane (dest = wave-uniform base + lane*16)
__device__ __forceinline__ void gll16(const void* g, void* l) {
  __builtin_amdgcn_global_load_lds(
      (const __attribute__((address_space(1))) void*)g,
      (__attribute__((address_space(3))) void*)l, 16, 0, 0);
}

// ---------------- fp32 -> bf16 cast, 7 tensors in one launch ----------------
struct CvtArgs {
  const float* src[7];
  unsigned short* dst[7];
  int n4[7];
};

__global__ __launch_bounds__(256) void cvt7_kernel(CvtArgs a) {
  const int z = blockIdx.y;
  const int i = blockIdx.x * 256 + threadIdx.x;
  if (i >= a.n4[z]) return;
  f32x4 v = ((const f32x4*)a.src[z])[i];
  u16x4 o;
  o[0] = f2bf(v[0]); o[1] = f2bf(v[1]); o[2] = f2bf(v[2]); o[3] = f2bf(v[3]);
  ((u16x4*)a.dst[z])[i] = o;
}

// -------- mask summary: flag per (b, 64-row q tile, 128-col k tile) ---------
__global__ __launch_bounds__(256) void mask_flags_kernel(const int* __restrict__ mask,
                                                         int* __restrict__ flags) {
  const int bid = blockIdx.x;  // b*512 + qt*16 + kt
  const int b = bid >> 9, qt = (bid >> 4) & 31, kt = bid & 15;
  __shared__ int sf;
  if (threadIdx.x == 0) sf = 0;
  __syncthreads();
  int any0 = 0;
  const size_t base = ((size_t)b * SS + qt * 64) * SS + kt * 128;
  for (int p = 0; p < 32; ++p) {
    int i = p * 256 + threadIdx.x;
    int r = i >> 7, col = i & 127;
    any0 |= (mask[base + (size_t)r * SS + col] == 0);
  }
  if (any0) sf = 1;  // benign same-value race
  __syncthreads();
  if (threadIdx.x == 0) flags[bid] = sf;
}

// ------------------- 128x128 tile GEMM: C = A * W^T + bias ------------------
// A [4096,1024] bf16 row-major, W [1024,1024] bf16 row-major (both K-contig).
// mode 0: bf16 out [B,H,S,dk]; mode 1: bf16 out [B,H,dk,S]; mode 2: f32 [B,S,D]
struct ProjArgs {
  const unsigned short* A[3];
  const unsigned short* W[3];
  const float* bias[3];
  void* out[3];
  float alpha[3];
  int mode[3];
};

__global__ __launch_bounds__(256, 2) void proj_gemm(ProjArgs args) {
  __shared__ unsigned short As[128][32];
  __shared__ unsigned short Bs[128][32];
  const int z = blockIdx.z;
  const unsigned short* __restrict__ A = args.A[z];
  const unsigned short* __restrict__ W = args.W[z];
  const float* __restrict__ bias = args.bias[z];
  const float alpha = args.alpha[z];
  const int mode = args.mode[z];

  const int tid = threadIdx.x;
  const int w = tid >> 6, lane = tid & 63;
  const int quad = lane >> 4, c = lane & 15;
  const int m0 = blockIdx.x * 128, n0 = blockIdx.y * 128;
  const int wm = (w >> 1) * 64, wn = (w & 1) * 64;
  const int sr = lane >> 2, scc = lane & 3;  // staging: 4 lanes x 16B per 64B row

  f32x4 acc[4][4];
#pragma unroll
  for (int i = 0; i < 4; ++i)
#pragma unroll
    for (int j = 0; j < 4; ++j) { f32x4 zz = {0.f, 0.f, 0.f, 0.f}; acc[i][j] = zz; }

  for (int kt = 0; kt < 32; ++kt) {
    const int k0 = kt * 32;
    __syncthreads();
#pragma unroll
    for (int t = 0; t < 2; ++t) {
      const int tt = w + t * 4;        // 8 calls of 1KB cover each 8KB tile
      const int r = tt * 16 + sr;
      gll16(A + (size_t)(m0 + r) * DM + k0 + scc * 8, &As[r][scc * 8]);
      gll16(W + (size_t)(n0 + r) * DM + k0 + scc * 8, &Bs[r][scc * 8]);
    }
    __syncthreads();
    bf16x8 af[4], bfr[4];
#pragma unroll
    for (int i = 0; i < 4; ++i) af[i] = *(const bf16x8*)&As[wm + i * 16 + c][quad * 8];
#pragma unroll
    for (int j = 0; j < 4; ++j) bfr[j] = *(const bf16x8*)&Bs[wn + j * 16 + c][quad * 8];
#pragma unroll
    for (int i = 0; i < 4; ++i)
#pragma unroll
      for (int j = 0; j < 4; ++j)
        acc[i][j] = __builtin_amdgcn_mfma_f32_16x16x32_bf16(af[i], bfr[j], acc[i][j], 0, 0, 0);
  }

#pragma unroll
  for (int i = 0; i < 4; ++i)
#pragma unroll
    for (int j = 0; j < 4; ++j)
#pragma unroll
      for (int r = 0; r < 4; ++r) {
        const int m = m0 + wm + i * 16 + quad * 4 + r;  // C/D: row=quad*4+reg
        const int n = n0 + wn + j * 16 + c;             //      col=lane&15
        const float val = (acc[i][j][r] + bias[n]) * alpha;
        if (mode == 2) {
          ((float*)args.out[z])[(size_t)m * DM + n] = val;
        } else {
          const int bb = m >> 11, s = m & 2047, hh = n >> 6, d = n & 63;
          size_t idx;
          if (mode == 0) idx = (((size_t)(bb * NH + hh)) * SS + s) * DKH + d;
          else           idx = (((size_t)(bb * NH + hh)) * DKH + d) * SS + s;
          ((unsigned short*)args.out[z])[idx] = f2bf(val);
        }
      }
}

// ------------------------------ flash attention -----------------------------
// Block: 64 q-rows (wave w owns rows w*16..w*16+15), k-tiles of 128.
// q already carries scale*log2e, so softmax uses raw exp2.
__global__ __launch_bounds__(256, 2) void attn_kernel(
    const unsigned short* __restrict__ qp, const unsigned short* __restrict__ kp,
    const unsigned short* __restrict__ vtp, const int* __restrict__ mask,
    const int* __restrict__ flags, unsigned short* __restrict__ xb) {
  __shared__ unsigned short Qs[2][64][32];   // [dk-chunk][q][32]  8KB
  __shared__ unsigned short Ks[2][128][32];  // [dk-chunk][s][32] 16KB
  __shared__ unsigned short Vt[4][64][32];   // [s-chunk][d][32]  16KB
  __shared__ unsigned short Ps[4][64][32];   // [s-chunk][q][32]  16KB

  const int tid = threadIdx.x;
  const int w = tid >> 6, lane = tid & 63;
  const int quad = lane >> 4, c = lane & 15;
  const int qt = blockIdx.x, bh = blockIdx.y;
  const int b = bh >> 4, h = bh & 15;
  const int q0 = qt * 64;
  const int sr = lane >> 2, scc = lane & 3;

#pragma unroll
  for (int t = 0; t < 2; ++t) {  // stage Q once: 8KB = 8 x 1KB calls
    const int tt = w + t * 4;
    const int kk = tt >> 2;
    const int r = (tt & 3) * 16 + sr;
    gll16(qp + ((size_t)bh * SS + q0 + r) * DKH + kk * 32 + scc * 8, &Qs[kk][r][scc * 8]);
  }

  f32x4 acco[4];
#pragma unroll
  for (int j = 0; j < 4; ++j) { f32x4 zz = {0.f, 0.f, 0.f, 0.f}; acco[j] = zz; }
  float m_run[4], l_run[4];
#pragma unroll
  for (int r = 0; r < 4; ++r) { m_run[r] = -3.0e38f; l_run[r] = 0.f; }

  for (int kt = 0; kt < 16; ++kt) {
    const int k0 = kt * 128;
    __syncthreads();  // prior PV done before restaging Ks/Vt
#pragma unroll
    for (int i = 0; i < 4; ++i) {
      const int tt = w * 4 + i;  // 16 calls each for Ks (16KB) and Vt (16KB)
      {
        const int kk = tt >> 3, r = (tt & 7) * 16 + sr;
        gll16(kp + ((size_t)bh * SS + k0 + r) * DKH + kk * 32 + scc * 8, &Ks[kk][r][scc * 8]);
      }
      {
        const int kc = tt >> 2, d = (tt & 3) * 16 + sr;
        gll16(vtp + ((size_t)bh * DKH + d) * SS + k0 + kc * 32 + scc * 8, &Vt[kc][d][scc * 8]);
      }
    }
    __syncthreads();

    // S = Q * K^T  (A-frag: m=lane&15, k=quad*8+j; B-frag: n=lane&15 same pattern)
    const bf16x8 aq0 = *(const bf16x8*)&Qs[0][w * 16 + c][quad * 8];
    const bf16x8 aq1 = *(const bf16x8*)&Qs[1][w * 16 + c][quad * 8];
    f32x4 accs[8];
#pragma unroll
    for (int j = 0; j < 8; ++j) { f32x4 zz = {0.f, 0.f, 0.f, 0.f}; accs[j] = zz; }
#pragma unroll
    for (int j = 0; j < 8; ++j) {
      const bf16x8 bk0 = *(const bf16x8*)&Ks[0][j * 16 + c][quad * 8];
      const bf16x8 bk1 = *(const bf16x8*)&Ks[1][j * 16 + c][quad * 8];
      accs[j] = __builtin_amdgcn_mfma_f32_16x16x32_bf16(aq0, bk0, accs[j], 0, 0, 0);
      accs[j] = __builtin_amdgcn_mfma_f32_16x16x32_bf16(aq1, bk1, accs[j], 0, 0, 0);
    }

    if (flags[((size_t)b * 32 + qt) * 16 + kt]) {  // uniform branch; all-ones -> skipped
#pragma unroll
      for (int j = 0; j < 8; ++j)
#pragma unroll
        for (int r = 0; r < 4; ++r) {
          const int qq = q0 + w * 16 + quad * 4 + r;
          const int kk2 = k0 + j * 16 + c;
          if (mask[((size_t)b * SS + qq) * SS + kk2] == 0) accs[j][r] = -1.0e30f;
        }
    }

    // online softmax; rows quad*4+r are replicated across the 16 lanes of a quad
    float al[4];
#pragma unroll
    for (int r = 0; r < 4; ++r) {
      float v = accs[0][r];
#pragma unroll
      for (int j = 1; j < 8; ++j) v = fmaxf(v, accs[j][r]);
      v = fmaxf(v, __shfl_xor(v, 1));
      v = fmaxf(v, __shfl_xor(v, 2));
      v = fmaxf(v, __shfl_xor(v, 4));
      v = fmaxf(v, __shfl_xor(v, 8));
      const float mn = fmaxf(m_run[r], v);
      al[r] = __builtin_amdgcn_exp2f(m_run[r] - mn);
      m_run[r] = mn;
      float s = 0.f;
#pragma unroll
      for (int j = 0; j < 8; ++j) {
        const float p = __builtin_amdgcn_exp2f(accs[j][r] - mn);
        s += p;
        // C-layout -> A-layout relayout through LDS (wave-private rows)
        Ps[j >> 1][w * 16 + quad * 4 + r][(j & 1) * 16 + c] = f2bf(p);
      }
      s += __shfl_xor(s, 1);
      s += __shfl_xor(s, 2);
      s += __shfl_xor(s, 4);
      s += __shfl_xor(s, 8);
      l_run[r] = l_run[r] * al[r] + s;
    }
#pragma unroll
    for (int j = 0; j < 4; ++j)
#pragma unroll
      for (int r = 0; r < 4; ++r) acco[j][r] *= al[r];

    // O += P * V   (a from Ps, b from Vt; both 64B-pitch -> conflict-free b128)
#pragma unroll
    for (int kc = 0; kc < 4; ++kc) {
      const bf16x8 ap = *(const bf16x8*)&Ps[kc][w * 16 + c][quad * 8];
#pragma unroll
      for (int j = 0; j < 4; ++j) {
        const bf16x8 bv = *(const bf16x8*)&Vt[kc][j * 16 + c][quad * 8];
        acco[j] = __builtin_amdgcn_mfma_f32_16x16x32_bf16(ap, bv, acco[j], 0, 0, 0);
      }
    }
  }

#pragma unroll
  for (int r = 0; r < 4; ++r) {
    const float inv = 1.0f / l_run[r];
    const int q = q0 + w * 16 + quad * 4 + r;
#pragma unroll
    for (int j = 0; j < 4; ++j) {
      xb[((size_t)b * SS + q) * DM + h * DKH + j * 16 + c] = f2bf(acco[j][r] * inv);
    }
  }
}

// ---------------------------------------------------------------------------
extern "C" void kernel_launch(void* const* d_in, const int* in_sizes, int n_in,
                              void* d_out, int out_size, void* d_ws, size_t ws_size,
                              hipStream_t stream) {
  (void)in_sizes; (void)n_in; (void)out_size; (void)ws_size;
  const float* query = (const float*)d_in[0];
  const float* key_  = (const float*)d_in[1];
  const float* value = (const float*)d_in[2];
  const int*   mask  = (const int*)d_in[3];
  const float* w_q = (const float*)d_in[4];
  const float* b_q = (const float*)d_in[5];
  const float* w_k = (const float*)d_in[6];
  const float* b_k = (const float*)d_in[7];
  const float* w_v = (const float*)d_in[8];
  const float* b_v = (const float*)d_in[9];
  const float* w_o = (const float*)d_in[10];
  const float* b_o = (const float*)d_in[11];

  char* ws = (char*)d_ws;
  const size_t SZ_IN = (size_t)MROWS * DM * 2;  // 8 MB
  const size_t SZ_W  = (size_t)DM * DM * 2;     // 2 MB
  unsigned short* qin = (unsigned short*)(ws);
  unsigned short* kin = (unsigned short*)(ws + SZ_IN);
  unsigned short* vin = (unsigned short*)(ws + 2 * SZ_IN);
  unsigned short* wqb = (unsigned short*)(ws + 3 * SZ_IN);
  unsigned short* wkb = (unsigned short*)(ws + 3 * SZ_IN + SZ_W);
  unsigned short* wvb = (unsigned short*)(ws + 3 * SZ_IN + 2 * SZ_W);
  unsigned short* wob = (unsigned short*)(ws + 3 * SZ_IN + 3 * SZ_W);
  unsigned short* qp  = (unsigned short*)(ws + 3 * SZ_IN + 4 * SZ_W);
  unsigned short* kp  = (unsigned short*)(ws + 4 * SZ_IN + 4 * SZ_W);
  unsigned short* vtp = (unsigned short*)(ws + 5 * SZ_IN + 4 * SZ_W);
  unsigned short* xb  = (unsigned short*)(ws + 6 * SZ_IN + 4 * SZ_W);
  int* flags          = (int*)(ws + 7 * SZ_IN + 4 * SZ_W);

  CvtArgs ca;
  ca.src[0] = query; ca.src[1] = key_; ca.src[2] = value;
  ca.src[3] = w_q; ca.src[4] = w_k; ca.src[5] = w_v; ca.src[6] = w_o;
  ca.dst[0] = qin; ca.dst[1] = kin; ca.dst[2] = vin;
  ca.dst[3] = wqb; ca.dst[4] = wkb; ca.dst[5] = wvb; ca.dst[6] = wob;
  ca.n4[0] = ca.n4[1] = ca.n4[2] = MROWS * DM / 4;
  ca.n4[3] = ca.n4[4] = ca.n4[5] = ca.n4[6] = DM * DM / 4;
  cvt7_kernel<<<dim3(4096, 7), 256, 0, stream>>>(ca);

  mask_flags_kernel<<<dim3(1024), 256, 0, stream>>>(mask, flags);

  ProjArgs pa;
  pa.A[0] = qin; pa.A[1] = kin; pa.A[2] = vin;
  pa.W[0] = wqb; pa.W[1] = wkb; pa.W[2] = wvb;
  pa.bias[0] = b_q; pa.bias[1] = b_k; pa.bias[2] = b_v;
  pa.out[0] = qp; pa.out[1] = kp; pa.out[2] = vtp;
  // fold softmax scale (1/sqrt(64)) * log2(e) into q so attention uses exp2
  pa.alpha[0] = 0.18033688011112042f; pa.alpha[1] = 1.f; pa.alpha[2] = 1.f;
  pa.mode[0] = 0; pa.mode[1] = 0; pa.mode[2] = 1;  // v stored transposed [B,H,dk,S]
  proj_gemm<<<dim3(32, 8, 3), 256, 0, stream>>>(pa);

  attn_kernel<<<dim3(32, 32), 256, 0, stream>>>(qp, kp, vtp, mask, flags, xb);

  ProjArgs po;
  po.A[0] = po.A[1] = po.A[2] = xb;
  po.W[0] = po.W[1] = po.W[2] = wob;
  po.bias[0] = po.bias[1] = po.bias[2] = b_o;
  po.out[0] = po.out[1] = po.out[2] = d_out;
  po.alpha[0] = po.alpha[1] = po.alpha[2] = 1.f;
  po.mode[0] = po.mode[1] = po.mode[2] = 2;
  proj_gemm<<<dim3(32, 8, 1), 256, 0, stream>>>(po);
}

// Round 2
// 299.317 us; speedup vs baseline: 1.0811x; 1.0811x over previous
//
#include <hip/hip_runtime.h>

typedef float f32x4 __attribute__((ext_vector_type(4)));
typedef short bf16x8 __attribute__((ext_vector_type(8)));
typedef unsigned short u16x4 __attribute__((ext_vector_type(4)));

#define BB 2
#define SS 2048
#define DM 1024
#define NH 16
#define DKH 64
#define MROWS 4096  // B*S

// RNE fp32 -> bf16
__device__ __forceinline__ unsigned short f2bf(float x) {
  union { float f; unsigned int u; } v; v.f = x;
  unsigned int r = v.u + 0x7fffu + ((v.u >> 16) & 1u);
  return (unsigned short)(r >> 16);
}

// async global->LDS, 16B per lane (dest = wave-uniform base + lane*16)
__device__ __forceinline__ void gll16(const void* g, void* l) {
  __builtin_amdgcn_global_load_lds(
      (const __attribute__((address_space(1))) void*)g,
      (__attribute__((address_space(3))) void*)l, 16, 0, 0);
}

// DPP cross-lane (VALU pipe, not DS) — reductions within 16-lane rows
template <int C>
__device__ __forceinline__ float dppf(float x) {
  return __builtin_bit_cast(float,
      __builtin_amdgcn_mov_dpp(__builtin_bit_cast(int, x), C, 0xf, 0xf, true));
}
__device__ __forceinline__ float rowmax16(float v) {
  v = fmaxf(v, dppf<0xB1>(v));   // quad_perm xor1
  v = fmaxf(v, dppf<0x4E>(v));   // quad_perm xor2
  v = fmaxf(v, dppf<0x141>(v));  // row_half_mirror (fold 8)
  v = fmaxf(v, dppf<0x140>(v));  // row_mirror (fold 16)
  return v;
}
__device__ __forceinline__ float rowsum16(float v) {
  v += dppf<0xB1>(v);
  v += dppf<0x4E>(v);
  v += dppf<0x141>(v);
  v += dppf<0x140>(v);
  return v;
}

// ---------------- fp32 -> bf16 cast, 7 tensors in one launch ----------------
struct CvtArgs {
  const float* src[7];
  unsigned short* dst[7];
  int n4[7];
};

__global__ __launch_bounds__(256) void cvt7_kernel(CvtArgs a) {
  const int z = blockIdx.y;
  const int i = blockIdx.x * 256 + threadIdx.x;
  if (i >= a.n4[z]) return;
  f32x4 v = ((const f32x4*)a.src[z])[i];
  u16x4 o;
  o[0] = f2bf(v[0]); o[1] = f2bf(v[1]); o[2] = f2bf(v[2]); o[3] = f2bf(v[3]);
  ((u16x4*)a.dst[z])[i] = o;
}

// -------- mask summary: flag per (b, 64-row q tile, 128-col k tile) ---------
__global__ __launch_bounds__(256) void mask_flags_kernel(const int* __restrict__ mask,
                                                         int* __restrict__ flags) {
  const int bid = blockIdx.x;  // b*512 + qt*16 + kt
  const int b = bid >> 9, qt = (bid >> 4) & 31, kt = bid & 15;
  __shared__ int sf;
  if (threadIdx.x == 0) sf = 0;
  __syncthreads();
  int any0 = 0;
  const size_t base = ((size_t)b * SS + qt * 64) * SS + kt * 128;
  for (int p = 0; p < 32; ++p) {
    int i = p * 256 + threadIdx.x;
    int r = i >> 7, col = i & 127;
    any0 |= (mask[base + (size_t)r * SS + col] == 0);
  }
  if (any0) sf = 1;  // benign same-value race
  __syncthreads();
  if (threadIdx.x == 0) flags[bid] = sf;
}

// ------------------- 128x128 tile GEMM: C = A * W^T + bias ------------------
// A [4096,1024] bf16 row-major, W [1024,1024] bf16 row-major (both K-contig).
// mode 0: bf16 out [B,H,S,dk]; mode 1: bf16 out [B,H,dk,S] with sigma-permuted
// s-order within each 128-block (matches attn PV fragment k-order);
// mode 2: f32 [B,S,D]
struct ProjArgs {
  const unsigned short* A[3];
  const unsigned short* W[3];
  const float* bias[3];
  void* out[3];
  float alpha[3];
  int mode[3];
};

__global__ __launch_bounds__(256, 2) void proj_gemm(ProjArgs args) {
  __shared__ unsigned short As[128][32];
  __shared__ unsigned short Bs[128][32];
  const int z = blockIdx.z;
  const unsigned short* __restrict__ A = args.A[z];
  const unsigned short* __restrict__ W = args.W[z];
  const float* __restrict__ bias = args.bias[z];
  const float alpha = args.alpha[z];
  const int mode = args.mode[z];

  const int tid = threadIdx.x;
  const int w = tid >> 6, lane = tid & 63;
  const int quad = lane >> 4, c = lane & 15;
  const int m0 = blockIdx.x * 128, n0 = blockIdx.y * 128;
  const int wm = (w >> 1) * 64, wn = (w & 1) * 64;
  const int sr = lane >> 2, scc = lane & 3;      // staging: 4 lanes x 16B per 64B row
  const int lx = scc ^ ((sr >> 1) & 3);          // xor-swizzled source chunk
  const int sk = (quad ^ ((c >> 1) & 3)) * 8;    // swizzled fragment read col

  f32x4 acc[4][4];
#pragma unroll
  for (int i = 0; i < 4; ++i)
#pragma unroll
    for (int j = 0; j < 4; ++j) { f32x4 zz = {0.f, 0.f, 0.f, 0.f}; acc[i][j] = zz; }

  for (int kt = 0; kt < 32; ++kt) {
    const int k0 = kt * 32;
    __syncthreads();
#pragma unroll
    for (int t = 0; t < 2; ++t) {
      const int tt = w + t * 4;        // 8 calls of 1KB cover each 8KB tile
      const int r = tt * 16 + sr;
      gll16(A + (size_t)(m0 + r) * DM + k0 + lx * 8, &As[r][scc * 8]);
      gll16(W + (size_t)(n0 + r) * DM + k0 + lx * 8, &Bs[r][scc * 8]);
    }
    __syncthreads();
    bf16x8 af[4], bfr[4];
#pragma unroll
    for (int i = 0; i < 4; ++i) af[i] = *(const bf16x8*)&As[wm + i * 16 + c][sk];
#pragma unroll
    for (int j = 0; j < 4; ++j) bfr[j] = *(const bf16x8*)&Bs[wn + j * 16 + c][sk];
#pragma unroll
    for (int i = 0; i < 4; ++i)
#pragma unroll
      for (int j = 0; j < 4; ++j)
        acc[i][j] = __builtin_amdgcn_mfma_f32_16x16x32_bf16(af[i], bfr[j], acc[i][j], 0, 0, 0);
  }

#pragma unroll
  for (int i = 0; i < 4; ++i)
#pragma unroll
    for (int j = 0; j < 4; ++j)
#pragma unroll
      for (int r = 0; r < 4; ++r) {
        const int m = m0 + wm + i * 16 + quad * 4 + r;  // C/D: row=quad*4+reg
        const int n = n0 + wn + j * 16 + c;             //      col=lane&15
        const float val = (acc[i][j][r] + bias[n]) * alpha;
        if (mode == 2) {
          ((float*)args.out[z])[(size_t)m * DM + n] = val;
        } else {
          const int bb = m >> 11, s = m & 2047, hh = n >> 6, d = n & 63;
          size_t idx;
          if (mode == 0) {
            idx = (((size_t)(bb * NH + hh)) * SS + s) * DKH + d;
          } else {
            // sigma-permuted V^T: stored pos within 128-block s.t. attn's
            // contiguous P-write k-order matches V fragment k-order
            const int sl = s & 127, blk = s >> 7;
            const int jj = sl >> 4, rem = sl & 15, kc = rem >> 2, qd = rem & 3;
            const int pos = kc * 32 + qd * 8 + jj;
            idx = (((size_t)(bb * NH + hh)) * DKH + d) * SS + blk * 128 + pos;
          }
          ((unsigned short*)args.out[z])[idx] = f2bf(val);
        }
      }
}

// ------------------------------ flash attention -----------------------------
// Block: 64 q-rows (wave w owns rows w*16..w*16+15), k-tiles of 128.
// q already carries scale*log2e, so softmax uses raw exp2.
// LDS 50176B -> 3 blocks/CU. Qs region is reused as Ps after Q-frag hoist.
__global__ __launch_bounds__(256, 3) void attn_kernel(
    const unsigned short* __restrict__ qp, const unsigned short* __restrict__ kp,
    const unsigned short* __restrict__ vtp, const int* __restrict__ mask,
    const int* __restrict__ flags, unsigned short* __restrict__ xb) {
  __shared__ __align__(16) char smem[50176];
  unsigned short (*Ks)[128][32] = (unsigned short (*)[128][32])smem;           // [2][128][32] 16KB
  unsigned short (*Vt)[64][32]  = (unsigned short (*)[64][32])(smem + 16384);  // [4][64][32]  16KB
  unsigned short (*Qs)[64][32]  = (unsigned short (*)[64][32])(smem + 32768);  // [2][64][32]   8KB
  unsigned short (*Ps)[136]     = (unsigned short (*)[136])(smem + 32768);     // [64][136] 17408B

  const int tid = threadIdx.x;
  const int w = tid >> 6, lane = tid & 63;
  const int quad = lane >> 4, c = lane & 15;
  const int qt = blockIdx.x, bh = blockIdx.y;
  const int b = bh >> 4, h = bh & 15;
  const int q0 = qt * 64;
  const int sr = lane >> 2, scc = lane & 3;
  const int lx = scc ^ ((sr >> 1) & 3);        // swizzled source chunk (staging)
  const int sk = (quad ^ ((c >> 1) & 3)) * 8;  // swizzled fragment read col

#pragma unroll
  for (int t = 0; t < 2; ++t) {  // stage Q once: 8KB = 8 x 1KB calls
    const int tt = w + t * 4;
    const int kk = tt >> 2;
    const int r = (tt & 3) * 16 + sr;
    gll16(qp + ((size_t)bh * SS + q0 + r) * DKH + kk * 32 + lx * 8, &Qs[kk][r][scc * 8]);
  }
  __syncthreads();
  // hoist Q fragments to registers; Qs LDS is dead after this (reused as Ps)
  const bf16x8 aq0 = *(const bf16x8*)&Qs[0][w * 16 + c][sk];
  const bf16x8 aq1 = *(const bf16x8*)&Qs[1][w * 16 + c][sk];

  f32x4 acco[4];
#pragma unroll
  for (int j = 0; j < 4; ++j) { f32x4 zz = {0.f, 0.f, 0.f, 0.f}; acco[j] = zz; }
  float m_run[4], l_run[4];
#pragma unroll
  for (int r = 0; r < 4; ++r) { m_run[r] = -3.0e38f; l_run[r] = 0.f; }

  for (int kt = 0; kt < 16; ++kt) {
    const int k0 = kt * 128;
    __syncthreads();  // prior PV done before restaging Ks/Vt
#pragma unroll
    for (int i = 0; i < 4; ++i) {
      const int tt = w * 4 + i;  // 16 calls each for Ks (16KB) and Vt (16KB)
      {
        const int kk = tt >> 3, r = (tt & 7) * 16 + sr;
        gll16(kp + ((size_t)bh * SS + k0 + r) * DKH + kk * 32 + lx * 8, &Ks[kk][r][scc * 8]);
      }
      {
        const int kc = tt >> 2, d = (tt & 3) * 16 + sr;
        gll16(vtp + ((size_t)bh * DKH + d) * SS + k0 + kc * 32 + lx * 8, &Vt[kc][d][scc * 8]);
      }
    }
    __syncthreads();

    // S = Q * K^T  (A-frag: m=lane&15, k=quad*8+j; B-frag: n=lane&15)
    f32x4 accs[8];
#pragma unroll
    for (int j = 0; j < 8; ++j) { f32x4 zz = {0.f, 0.f, 0.f, 0.f}; accs[j] = zz; }
#pragma unroll
    for (int j = 0; j < 8; ++j) {
      const int rowk = j * 16 + c;
      const bf16x8 bk0 = *(const bf16x8*)&Ks[0][rowk][sk];
      const bf16x8 bk1 = *(const bf16x8*)&Ks[1][rowk][sk];
      accs[j] = __builtin_amdgcn_mfma_f32_16x16x32_bf16(aq0, bk0, accs[j], 0, 0, 0);
      accs[j] = __builtin_amdgcn_mfma_f32_16x16x32_bf16(aq1, bk1, accs[j], 0, 0, 0);
    }

    if (flags[((size_t)b * 32 + qt) * 16 + kt]) {  // uniform branch; all-ones -> skipped
#pragma unroll
      for (int j = 0; j < 8; ++j)
#pragma unroll
        for (int r = 0; r < 4; ++r) {
          const int qq = q0 + w * 16 + quad * 4 + r;
          const int kk2 = k0 + j * 16 + c;
          if (mask[((size_t)b * SS + qq) * SS + kk2] == 0) accs[j][r] = -1.0e30f;
        }
    }

    // online softmax; row r of this wave's quad lives in the quad's 16 lanes
    float al[4];
#pragma unroll
    for (int r = 0; r < 4; ++r) {
      float v = accs[0][r];
#pragma unroll
      for (int j = 1; j < 8; ++j) v = fmaxf(v, accs[j][r]);
      v = rowmax16(v);
      const float mn = fmaxf(m_run[r], v);
      al[r] = __builtin_amdgcn_exp2f(m_run[r] - mn);
      m_run[r] = mn;
      float s = 0.f;
      union { bf16x8 v8; unsigned short u[8]; } pk;
#pragma unroll
      for (int j = 0; j < 8; ++j) {
        const float p = __builtin_amdgcn_exp2f(accs[j][r] - mn);
        union { float f; unsigned int u; } pv; pv.f = p;
        pk.u[j] = (unsigned short)(pv.u >> 16);  // RTZ
        // sum the ROUNDED p so rounding bias cancels in the l-normalization
        union { unsigned int u; float f; } pr; pr.u = pv.u & 0xffff0000u;
        s += pr.f;
      }
      // one b128 write: lane's 8 p's are contiguous (k = c + 16j at col c*8+j)
      *(bf16x8*)&Ps[w * 16 + quad * 4 + r][c * 8] = pk.v8;
      s = rowsum16(s);
      l_run[r] = l_run[r] * al[r] + s;
    }
#pragma unroll
    for (int j = 0; j < 4; ++j)
#pragma unroll
      for (int r = 0; r < 4; ++r) acco[j][r] *= al[r];

    // O += P * V ; A-frag k at (kc,quad,jj) = 4kc+quad+16jj, matches
    // sigma-permuted Vt (global layout) read through the xor swizzle.
#pragma unroll
    for (int kc = 0; kc < 4; ++kc) {
      const bf16x8 ap = *(const bf16x8*)&Ps[w * 16 + c][kc * 32 + quad * 8];
#pragma unroll
      for (int j = 0; j < 4; ++j) {
        const bf16x8 bv = *(const bf16x8*)&Vt[kc][j * 16 + c][sk];
        acco[j] = __builtin_amdgcn_mfma_f32_16x16x32_bf16(ap, bv, acco[j], 0, 0, 0);
      }
    }
  }

#pragma unroll
  for (int r = 0; r < 4; ++r) {
    const float inv = 1.0f / l_run[r];
    const int q = q0 + w * 16 + quad * 4 + r;
#pragma unroll
    for (int j = 0; j < 4; ++j) {
      xb[((size_t)b * SS + q) * DM + h * DKH + j * 16 + c] = f2bf(acco[j][r] * inv);
    }
  }
}

// ---------------------------------------------------------------------------
extern "C" void kernel_launch(void* const* d_in, const int* in_sizes, int n_in,
                              void* d_out, int out_size, void* d_ws, size_t ws_size,
                              hipStream_t stream) {
  (void)in_sizes; (void)n_in; (void)out_size; (void)ws_size;
  const float* query = (const float*)d_in[0];
  const float* key_  = (const float*)d_in[1];
  const float* value = (const float*)d_in[2];
  const int*   mask  = (const int*)d_in[3];
  const float* w_q = (const float*)d_in[4];
  const float* b_q = (const float*)d_in[5];
  const float* w_k = (const float*)d_in[6];
  const float* b_k = (const float*)d_in[7];
  const float* w_v = (const float*)d_in[8];
  const float* b_v = (const float*)d_in[9];
  const float* w_o = (const float*)d_in[10];
  const float* b_o = (const float*)d_in[11];

  char* ws = (char*)d_ws;
  const size_t SZ_IN = (size_t)MROWS * DM * 2;  // 8 MB
  const size_t SZ_W  = (size_t)DM * DM * 2;     // 2 MB
  unsigned short* qin = (unsigned short*)(ws);
  unsigned short* kin = (unsigned short*)(ws + SZ_IN);
  unsigned short* vin = (unsigned short*)(ws + 2 * SZ_IN);
  unsigned short* wqb = (unsigned short*)(ws + 3 * SZ_IN);
  unsigned short* wkb = (unsigned short*)(ws + 3 * SZ_IN + SZ_W);
  unsigned short* wvb = (unsigned short*)(ws + 3 * SZ_IN + 2 * SZ_W);
  unsigned short* wob = (unsigned short*)(ws + 3 * SZ_IN + 3 * SZ_W);
  unsigned short* qp  = (unsigned short*)(ws + 3 * SZ_IN + 4 * SZ_W);
  unsigned short* kp  = (unsigned short*)(ws + 4 * SZ_IN + 4 * SZ_W);
  unsigned short* vtp = (unsigned short*)(ws + 5 * SZ_IN + 4 * SZ_W);
  unsigned short* xb  = (unsigned short*)(ws + 6 * SZ_IN + 4 * SZ_W);
  int* flags          = (int*)(ws + 7 * SZ_IN + 4 * SZ_W);

  CvtArgs ca;
  ca.src[0] = query; ca.src[1] = key_; ca.src[2] = value;
  ca.src[3] = w_q; ca.src[4] = w_k; ca.src[5] = w_v; ca.src[6] = w_o;
  ca.dst[0] = qin; ca.dst[1] = kin; ca.dst[2] = vin;
  ca.dst[3] = wqb; ca.dst[4] = wkb; ca.dst[5] = wvb; ca.dst[6] = wob;
  ca.n4[0] = ca.n4[1] = ca.n4[2] = MROWS * DM / 4;
  ca.n4[3] = ca.n4[4] = ca.n4[5] = ca.n4[6] = DM * DM / 4;
  cvt7_kernel<<<dim3(4096, 7), 256, 0, stream>>>(ca);

  mask_flags_kernel<<<dim3(1024), 256, 0, stream>>>(mask, flags);

  ProjArgs pa;
  pa.A[0] = qin; pa.A[1] = kin; pa.A[2] = vin;
  pa.W[0] = wqb; pa.W[1] = wkb; pa.W[2] = wvb;
  pa.bias[0] = b_q; pa.bias[1] = b_k; pa.bias[2] = b_v;
  pa.out[0] = qp; pa.out[1] = kp; pa.out[2] = vtp;
  // fold softmax scale (1/sqrt(64)) * log2(e) into q so attention uses exp2
  pa.alpha[0] = 0.18033688011112042f; pa.alpha[1] = 1.f; pa.alpha[2] = 1.f;
  pa.mode[0] = 0; pa.mode[1] = 0; pa.mode[2] = 1;  // v: sigma-permuted [B,H,dk,S]
  proj_gemm<<<dim3(32, 8, 3), 256, 0, stream>>>(pa);

  attn_kernel<<<dim3(32, 32), 256, 0, stream>>>(qp, kp, vtp, mask, flags, xb);

  ProjArgs po;
  po.A[0] = po.A[1] = po.A[2] = xb;
  po.W[0] = po.W[1] = po.W[2] = wob;
  po.bias[0] = po.bias[1] = po.bias[2] = b_o;
  po.out[0] = po.out[1] = po.out[2] = d_out;
  po.alpha[0] = po.alpha[1] = po.alpha[2] = 1.f;
  po.mode[0] = po.mode[1] = po.mode[2] = 2;
  proj_gemm<<<dim3(32, 8, 1), 256, 0, stream>>>(po);
}